// Round 6
// baseline (195.160 us; speedup 1.0000x reference)
//
#include <hip/hip_runtime.h>

#define N_NODES 100000
#define N_EDGES 3200000
#define NVEC    (N_EDGES / 4)           // 800000 int4 per stream

#define S_LOG2  7
#define S       (1 << S_LOG2)           // 128 nodes per partition
#define NPART   ((N_NODES + S - 1) / S) // 782 partitions ~ 3.05 x 256 CUs
#define NPB     832                     // NPART padded to x64 for the scan
#define GSTRIDE 16                      // gcur padded to 64B/counter (L2 spread)

#define EPB     6144                    // edges per bin block: nv = 1536 = 3*512
#define NB      ((N_EDGES + EPB - 1) / EPB)  // 521 blocks
#define CAP     4992                    // bucket capacity (mean 4092, ~14 sigma)

constexpr float DSIGMA_DT  = -0.0001f;
constexpr float PHI_THRESH = 0.3f;
constexpr float EPS        = 1e-8f;

// ---------------- Pass A: counting-sort edges into 782 partition buckets ---
// Register-resident edges: ONE global read of the edge list, ONE returning
// LDS atomic per edge (rank into registers), ONE packed u64 LDS scatter,
// ONE b64 read at copyout -> 3 LDS lane-ops/edge.
// 58 KB LDS -> 2 blocks/CU; launch_bounds(512,4) so VGPRs (~50) never spill.
__global__ __launch_bounds__(512, 4) void bin_kernel(
        const int4* __restrict__ ei4,
        const float* __restrict__ x,
        const float* __restrict__ pos,
        float4* __restrict__ posT,
        int* __restrict__ gcur,
        int* __restrict__ buckets) {
    __shared__ unsigned long long l64[EPB]; // 48 KB packed {bin,entry}, sorted
    __shared__ int hist[NPB], lofs[NPB];    // 6.7 KB
    __shared__ int baseg[NPART];            // 3.1 KB
    const int tid = threadIdx.x;

    // fused prep: slice of posT
    {
        const int per = (N_NODES + NB - 1) / NB;   // 192
        const int lo = blockIdx.x * per;
        const int hi = min(lo + per, N_NODES);
        for (int i = lo + tid; i < hi; i += 512)
            posT[i] = make_float4(pos[3 * i], pos[3 * i + 1], pos[3 * i + 2],
                                  x[9 * i + 3]);
    }

    const int ebase = blockIdx.x * EPB;
    const int n  = min(EPB, N_EDGES - ebase);   // multiple of 4
    const int nv = n >> 2;
    const int4* __restrict__ src4 = ei4 + (ebase >> 2);
    const int4* __restrict__ dst4 = ei4 + NVEC + (ebase >> 2);

    for (int i = tid; i < NPB; i += 512) hist[i] = 0;
    __syncthreads();

    // loop 1: single global read of edges into REGISTERS; histogram with
    // rank capture into REGISTERS (1 LDS atomic per edge, nothing else)
    int4 rs[3], rd[3];
    unsigned short rk[12];
#pragma unroll
    for (int k = 0; k < 3; ++k) {
        int v = tid + k * 512;
        if (v < nv) {
            rs[k] = src4[v];
            rd[k] = dst4[v];
            rk[4 * k + 0] = (unsigned short)atomicAdd(&hist[rd[k].x >> S_LOG2], 1);
            rk[4 * k + 1] = (unsigned short)atomicAdd(&hist[rd[k].y >> S_LOG2], 1);
            rk[4 * k + 2] = (unsigned short)atomicAdd(&hist[rd[k].z >> S_LOG2], 1);
            rk[4 * k + 3] = (unsigned short)atomicAdd(&hist[rd[k].w >> S_LOG2], 1);
        }
    }
    __syncthreads();

    // wave-0 exclusive prefix over 832 padded bins (13 x 64 with carry)
    if (tid < 64) {
        int carry = 0;
        for (int b = 0; b < NPB; b += 64) {
            int v = hist[b + tid];
            int orig = v;
#pragma unroll
            for (int d = 1; d < 64; d <<= 1) {
                int t = __shfl_up(v, d, 64);
                if (tid >= d) v += t;
            }
            lofs[b + tid] = carry + v - orig;
            carry += __shfl(v, 63, 64);
        }
    }
    __syncthreads();
    for (int i = tid; i < NPART; i += 512)
        baseg[i] = atomicAdd(&gcur[i * GSTRIDE], hist[i]);
    __syncthreads();

    // loop 2: scatter from registers into bin-sorted LDS (1 u64 write/edge)
#pragma unroll
    for (int k = 0; k < 3; ++k) {
        int v = tid + k * 512;
        if (v < nv) {
#pragma unroll
            for (int j = 0; j < 4; ++j) {
                int dk = j == 0 ? rd[k].x : j == 1 ? rd[k].y : j == 2 ? rd[k].z : rd[k].w;
                int sk = j == 0 ? rs[k].x : j == 1 ? rs[k].y : j == 2 ? rs[k].z : rs[k].w;
                int bin = dk >> S_LOG2;
                int pos = lofs[bin] + (int)rk[4 * k + j];
                l64[pos] = ((unsigned long long)(unsigned)bin << 32)
                         | (unsigned)((sk << S_LOG2) | (dk & (S - 1)));
            }
        }
    }
    __syncthreads();

    // dense coalesced copy-out (1 b64 read/edge; ~8-entry runs per bin)
    for (int i = tid; i < n; i += 512) {
        unsigned long long t = l64[i];
        int b = (int)(t >> 32);
        int e = (int)(unsigned)t;
        int pos = baseg[b] + (i - lofs[b]);
        if (pos < CAP) buckets[(size_t)b * CAP + pos] = e;
    }
}

// ---------------- Pass B: direct accumulation, BANK-STAGGERED LDS atomics --
// One pass over the bucket: coalesced entry read, L2-hot posT[src] gather,
// 4 NON-RETURNING ds_add_f32 to acc[c*(S+1)+d] -> bank (c+d)%32, so an
// edge's 4 atomics hit 4 distinct banks and each wave-instruction spreads
// uniformly (~2-way, free). No rank atomics, no S2/RK bounce, no scan, no
// gather-tail imbalance. Fused finalize writes `out` directly.
// (R1's version of this idea put all 4 atomics on ONE bank - 4KB-aligned
// arrays - which is why it measured 59 us. Stagger is the fix.)
__global__ __launch_bounds__(512, 8) void part_kernel(
        const int* __restrict__ gcur,
        const int* __restrict__ buckets,
        const float4* __restrict__ posT,
        const float* __restrict__ x,
        float* __restrict__ out) {
    __shared__ float acc[4 * (S + 1)];     // 2.1 KB staggered accumulators
    __shared__ float4 ploc[S];             // 2 KB partition's posT slice
    const int p = blockIdx.x, tid = threadIdx.x;
    const int lo = p << S_LOG2;

    if (tid < S) {
        int node = lo + tid;
        ploc[tid] = (node < N_NODES) ? posT[node] : make_float4(0.f, 0.f, 0.f, 0.f);
    }
    if (tid < 4 * (S + 1)) acc[tid] = 0.f;
    const int len = min(gcur[p * GSTRIDE], CAP);
    const int* __restrict__ bp = buckets + (size_t)p * CAP;
    __syncthreads();

    // single edge-parallel pass, uniform work per edge
    for (int i = tid; i < len; i += 512) {
        int v = bp[i];
        int d = v & (S - 1);
        int s = v >> S_LOG2;
        float4 a = posT[s];
        float4 b = ploc[d];
        float px = a.x - b.x, py = a.y - b.y, pz = a.z - b.z;
        float dT = a.w - b.w;
        float w  = dT / (px * px + py * py + pz * pz + EPS);
        atomicAdd(&acc[d],               w * px);   // bank (d+0)%32
        atomicAdd(&acc[(S + 1) + d],     w * py);   // bank (d+1)%32
        atomicAdd(&acc[2 * (S + 1) + d], w * pz);   // bank (d+2)%32
        atomicAdd(&acc[3 * (S + 1) + d], 1.0f);     // bank (d+3)%32
    }
    __syncthreads();

    // fused finalize: mask * DSIGMA_DT / max(cnt,1), write out directly
    if (tid < S) {
        int node = lo + tid;
        if (node < N_NODES) {
            float ax = acc[tid];
            float ay = acc[(S + 1) + tid];
            float az = acc[2 * (S + 1) + tid];
            float aw = acc[3 * (S + 1) + tid];
            float phi = x[node * 9 + 8];
            float cn = aw > 1.0f ? aw : 1.0f;
            float m = (fabsf(phi) < PHI_THRESH) ? (DSIGMA_DT / cn) : 0.0f;
            out[3 * node]     = m * ax;
            out[3 * node + 1] = m * ay;
            out[3 * node + 2] = m * az;
        }
    }
}

// ---------------- fallback: global atomics (small ws) ---------------------
__global__ void prep_kernel(const float* __restrict__ x,
                            const float* __restrict__ pos,
                            float4* __restrict__ posT) {
    int i = blockIdx.x * blockDim.x + threadIdx.x;
    if (i < N_NODES)
        posT[i] = make_float4(pos[3 * i], pos[3 * i + 1], pos[3 * i + 2],
                              x[9 * i + 3]);
}

__global__ void edge_scatter_atomic_kernel(const int* __restrict__ ei,
                                           const float4* __restrict__ posT,
                                           float4* __restrict__ accum) {
    int e = blockIdx.x * blockDim.x + threadIdx.x;
    if (e >= N_EDGES) return;
    int s = ei[e];
    int d = ei[N_EDGES + e];
    float4 a = posT[s];
    float4 b = posT[d];
    float px = a.x - b.x, py = a.y - b.y, pz = a.z - b.z;
    float dT = a.w - b.w;
    float w  = dT / (px * px + py * py + pz * pz + EPS);
    float* ac = (float*)&accum[d];
    atomicAdd(ac,     w * px);
    atomicAdd(ac + 1, w * py);
    atomicAdd(ac + 2, w * pz);
    atomicAdd(ac + 3, 1.0f);
}

__global__ void finalize_accum_kernel(const float* __restrict__ x,
                                      const float4* __restrict__ accum,
                                      float* __restrict__ out) {
    int i = blockIdx.x * blockDim.x + threadIdx.x;
    if (i >= N_NODES) return;
    float4 a = accum[i];
    float phi = x[i * 9 + 8];
    float cn = a.w > 1.0f ? a.w : 1.0f;
    float m = (fabsf(phi) < PHI_THRESH) ? (DSIGMA_DT / cn) : 0.0f;
    out[3 * i]     = m * a.x;
    out[3 * i + 1] = m * a.y;
    out[3 * i + 2] = m * a.z;
}

extern "C" void kernel_launch(void* const* d_in, const int* in_sizes, int n_in,
                              void* d_out, int out_size, void* d_ws, size_t ws_size,
                              hipStream_t stream) {
    const float* x   = (const float*)d_in[0];
    const float* pos = (const float*)d_in[1];
    const int*   ei  = (const int*)d_in[2];
    float* out = (float*)d_out;

    // ws layout: [posT 1.6MB][gcur 64KB padded][buckets 15.6MB]
    const size_t posT_b = (size_t)N_NODES * sizeof(float4);             // 1.6 MB
    const size_t gcur_b = 65536;                                        // 782 x 64B
    const size_t buck_b = (size_t)NPART * CAP * sizeof(int);            // 15.6 MB

    char* w = (char*)d_ws;
    float4* posT    = (float4*)w;
    int*    gcur    = (int*)(w + posT_b);
    int*    buckets = (int*)(w + posT_b + gcur_b);

    const size_t need_full = posT_b + gcur_b + buck_b;                  // ~17.3 MB

    const int B = 256;

    if (ws_size >= need_full) {
        hipMemsetAsync(gcur, 0, gcur_b, stream);
        bin_kernel<<<NB, 512, 0, stream>>>((const int4*)ei, x, pos, posT, gcur, buckets);
        part_kernel<<<NPART, 512, 0, stream>>>(gcur, buckets, posT, x, out);
    } else {
        float4* accum = (float4*)(w + posT_b);  // 1.6 MB
        prep_kernel<<<(N_NODES + B - 1) / B, B, 0, stream>>>(x, pos, posT);
        hipMemsetAsync(accum, 0, (size_t)N_NODES * sizeof(float4), stream);
        edge_scatter_atomic_kernel<<<(N_EDGES + B - 1) / B, B, 0, stream>>>(ei, posT, accum);
        finalize_accum_kernel<<<(N_NODES + B - 1) / B, B, 0, stream>>>(x, accum, out);
    }
}

// Round 8
// 119.412 us; speedup vs baseline: 1.6343x; 1.6343x over previous
//
#include <hip/hip_runtime.h>

#define N_NODES 100000
#define N_EDGES 3200000
#define NVEC    (N_EDGES / 4)           // 800000 int4 per stream

#define S_LOG2  8
#define S       (1 << S_LOG2)           // 256 nodes per partition
#define NPART   ((N_NODES + S - 1) / S) // 391 partitions
#define NPB     448                     // NPART padded to x64 for the scan
#define GSTRIDE 16                      // gcur padded to 64B/counter (L2 spread)

#define EPB     6252                    // edges per bin block (mult of 4)
#define NB      ((N_EDGES + EPB - 1) / EPB)  // 512 blocks
#define CAP     9216                    // bucket capacity (mean 8184, +11 sigma)
#define KPT     18                      // part: max bucket entries per thread (18*512=9216)

constexpr float DSIGMA_DT  = -0.0001f;
constexpr float PHI_THRESH = 0.3f;
constexpr float EPS        = 1e-8f;

// ---------------- Pass A: counting-sort edges into 391 partition buckets ---
// S=256 -> ~16 entries per bin per block = 64B runs, so bucket cache lines
// are mostly written WHOLE by a single block (kills the cross-XCD
// partial-line false sharing that caused 4.5x HBM write amplification at
// 4-entry runs in R4). 1 returning LDS atomic per edge (rank capture);
// scatter/copy-out are plain LDS/global ops. 55 KB LDS -> 2 blocks/CU.
__global__ __launch_bounds__(512) void bin_kernel(const int4* __restrict__ ei4,
                                                  const float* __restrict__ x,
                                                  const float* __restrict__ pos,
                                                  float4* __restrict__ posT,
                                                  int* __restrict__ gcur,
                                                  int* __restrict__ buckets) {
    __shared__ int   lbuf[EPB];            // 25 KB sorted entries (sk<<8 | dk&255)
    __shared__ unsigned short lrk[EPB];    // 12.5 KB per-entry rank
    __shared__ unsigned short lbinS[EPB];  // 12.5 KB bin id of sorted entry
    __shared__ int hist[NPB], lofs[NPB];   // 3.5 KB
    __shared__ int baseg[NPART];           // 1.6 KB
    const int tid = threadIdx.x;

    // fused prep: slice of posT
    {
        const int per = (N_NODES + NB - 1) / NB;   // 196
        const int lo = blockIdx.x * per;
        const int hi = min(lo + per, N_NODES);
        for (int i = lo + tid; i < hi; i += 512)
            posT[i] = make_float4(pos[3 * i], pos[3 * i + 1], pos[3 * i + 2],
                                  x[9 * i + 3]);
    }

    const int ebase = blockIdx.x * EPB;
    const int n  = min(EPB, N_EDGES - ebase);   // multiple of 4
    const int nv = n >> 2;
    const int4* __restrict__ src4 = ei4 + (ebase >> 2);
    const int4* __restrict__ dst4 = ei4 + NVEC + (ebase >> 2);

    for (int i = tid; i < NPB; i += 512) hist[i] = 0;
    __syncthreads();

    // loop 1: histogram with rank capture (1 returning LDS atomic per edge)
    for (int v = tid; v < nv; v += 512) {
        int4 d = dst4[v];
        ushort4 rk;
        rk.x = (unsigned short)atomicAdd(&hist[d.x >> S_LOG2], 1);
        rk.y = (unsigned short)atomicAdd(&hist[d.y >> S_LOG2], 1);
        rk.z = (unsigned short)atomicAdd(&hist[d.z >> S_LOG2], 1);
        rk.w = (unsigned short)atomicAdd(&hist[d.w >> S_LOG2], 1);
        ((ushort4*)lrk)[v] = rk;
    }
    __syncthreads();

    // wave-0 exclusive prefix over 448 padded bins (7 x 64 with carry)
    if (tid < 64) {
        int carry = 0;
        for (int b = 0; b < NPB; b += 64) {
            int v = hist[b + tid];
            int orig = v;
#pragma unroll
            for (int d = 1; d < 64; d <<= 1) {
                int t = __shfl_up(v, d, 64);
                if (tid >= d) v += t;
            }
            lofs[b + tid] = carry + v - orig;
            carry += __shfl(v, 63, 64);
        }
    }
    __syncthreads();
    if (tid < NPART)
        baseg[tid] = atomicAdd(&gcur[tid * GSTRIDE], hist[tid]);
    __syncthreads();

    // loop 2: re-read edge slice (L2-hot), place entries with plain writes
    for (int v = tid; v < nv; v += 512) {
        int4 s = src4[v];
        int4 d = dst4[v];
        ushort4 rk = ((const ushort4*)lrk)[v];
#pragma unroll
        for (int k = 0; k < 4; ++k) {
            int dk = k == 0 ? d.x : k == 1 ? d.y : k == 2 ? d.z : d.w;
            int sk = k == 0 ? s.x : k == 1 ? s.y : k == 2 ? s.z : s.w;
            int rr = k == 0 ? rk.x : k == 1 ? rk.y : k == 2 ? rk.z : rk.w;
            int bin = dk >> S_LOG2;
            int pos = lofs[bin] + rr;
            lbuf[pos]  = (sk << S_LOG2) | (dk & (S - 1));
            lbinS[pos] = (unsigned short)bin;
        }
    }
    __syncthreads();

    // dense coalesced copy-out (~16-entry = 64B runs per bin)
    for (int i = tid; i < n; i += 512) {
        int b   = lbinS[i];
        int pos = baseg[b] + (i - lofs[b]);
        if (pos < CAP) buckets[(size_t)b * CAP + pos] = lbuf[i];
    }
}

// ---------------- Pass B: one block per partition, fused finalize ----------
// In-LDS counting sort to node order: ranks held in REGISTERS (1 returning
// LDS atomic/edge, single global bucket read), then a 2-thread-per-node
// segmented register reduce (pair shuffle combine) and fused
// mask * DSIGMA_DT / cnt epilogue writing `out` directly.
// 42.9 KB LDS -> 3 blocks/CU at launch_bounds(512,6).
__global__ __launch_bounds__(512, 6) void part_kernel(
        const int* __restrict__ gcur,
        const int* __restrict__ buckets,
        const float4* __restrict__ posT,
        const float* __restrict__ x,
        float* __restrict__ out) {
    __shared__ int S2[CAP];                // 36 KB dst-sorted src ids
    __shared__ int hist[S], base[S];       // 2 KB
    __shared__ float4 ploc[S];             // 4 KB partition's posT slice
    const int p = blockIdx.x, tid = threadIdx.x;
    const int lo = p << S_LOG2;

    if (tid < S) {
        hist[tid] = 0;
        int node = lo + tid;
        ploc[tid] = (node < N_NODES) ? posT[node] : make_float4(0.f, 0.f, 0.f, 0.f);
    }
    const int len = min(gcur[p * GSTRIDE], CAP);
    const int* __restrict__ bp = buckets + (size_t)p * CAP;
    __syncthreads();

    // pass 1: load entries to registers + rank capture (1 LDS atomic/edge)
    int ent[KPT];
    unsigned short prk[KPT];
#pragma unroll
    for (int k = 0; k < KPT; ++k) {
        int i = tid + k * 512;
        ent[k] = 0;
        if (i < len) {
            ent[k] = bp[i];
            prk[k] = (unsigned short)atomicAdd(&hist[ent[k] & (S - 1)], 1);
        }
    }
    __syncthreads();

    // exclusive prefix scan of hist[0..256) by wave 0 (4 x 64 with carry)
    if (tid < 64) {
        int carry = 0;
        for (int b = 0; b < S; b += 64) {
            int v = hist[b + tid];
            int orig = v;
#pragma unroll
            for (int d = 1; d < 64; d <<= 1) {
                int t = __shfl_up(v, d, 64);
                if (tid >= d) v += t;
            }
            base[b + tid] = carry + v - orig;
            carry += __shfl(v, 63, 64);
        }
    }
    __syncthreads();

    // pass 2: scatter from registers into dst-sorted order (1 LDS write/edge)
#pragma unroll
    for (int k = 0; k < KPT; ++k) {
        int i = tid + k * 512;
        if (i < len)
            S2[base[ent[k] & (S - 1)] + (int)prk[k]] = ent[k] >> S_LOG2;
    }
    __syncthreads();

    // fused reduce + finalize: 2 threads per node, pair shuffle combine.
    // tid = r*2 + q ; rows r in [0,256), q in [0,2). 512 = S*2 exactly.
    const int r = tid >> 1, q = tid & 1;
    const int node = lo + r;
    const int nseg = hist[r];
    const int b0 = base[r];
    float4 b = ploc[r];
    float ax = 0.f, ay = 0.f, az = 0.f;
    for (int j = b0 + q; j < b0 + nseg; j += 2) {
        float4 a = posT[S2[j]];
        float px = a.x - b.x, py = a.y - b.y, pz = a.z - b.z;
        float dT = a.w - b.w;
        float w  = dT / (px * px + py * py + pz * pz + EPS);
        ax += w * px; ay += w * py; az += w * pz;
    }
    // combine q=0/1 (lanes r*2, r*2+1 are adjacent within a wave)
    ax += __shfl_down(ax, 1, 64);
    ay += __shfl_down(ay, 1, 64);
    az += __shfl_down(az, 1, 64);
    if (q == 0 && node < N_NODES) {
        float phi = x[node * 9 + 8];
        float cn = nseg > 1 ? (float)nseg : 1.0f;
        float m = (fabsf(phi) < PHI_THRESH) ? (DSIGMA_DT / cn) : 0.0f;
        out[3 * node]     = m * ax;
        out[3 * node + 1] = m * ay;
        out[3 * node + 2] = m * az;
    }
}

// ---------------- fallback: global atomics (small ws) ---------------------
__global__ void prep_kernel(const float* __restrict__ x,
                            const float* __restrict__ pos,
                            float4* __restrict__ posT) {
    int i = blockIdx.x * blockDim.x + threadIdx.x;
    if (i < N_NODES)
        posT[i] = make_float4(pos[3 * i], pos[3 * i + 1], pos[3 * i + 2],
                              x[9 * i + 3]);
}

__global__ void edge_scatter_atomic_kernel(const int* __restrict__ ei,
                                           const float4* __restrict__ posT,
                                           float4* __restrict__ accum) {
    int e = blockIdx.x * blockDim.x + threadIdx.x;
    if (e >= N_EDGES) return;
    int s = ei[e];
    int d = ei[N_EDGES + e];
    float4 a = posT[s];
    float4 b = posT[d];
    float px = a.x - b.x, py = a.y - b.y, pz = a.z - b.z;
    float dT = a.w - b.w;
    float w  = dT / (px * px + py * py + pz * pz + EPS);
    float* ac = (float*)&accum[d];
    atomicAdd(ac,     w * px);
    atomicAdd(ac + 1, w * py);
    atomicAdd(ac + 2, w * pz);
    atomicAdd(ac + 3, 1.0f);
}

__global__ void finalize_accum_kernel(const float* __restrict__ x,
                                      const float4* __restrict__ accum,
                                      float* __restrict__ out) {
    int i = blockIdx.x * blockDim.x + threadIdx.x;
    if (i >= N_NODES) return;
    float4 a = accum[i];
    float phi = x[i * 9 + 8];
    float cn = a.w > 1.0f ? a.w : 1.0f;
    float m = (fabsf(phi) < PHI_THRESH) ? (DSIGMA_DT / cn) : 0.0f;
    out[3 * i]     = m * a.x;
    out[3 * i + 1] = m * a.y;
    out[3 * i + 2] = m * a.z;
}

extern "C" void kernel_launch(void* const* d_in, const int* in_sizes, int n_in,
                              void* d_out, int out_size, void* d_ws, size_t ws_size,
                              hipStream_t stream) {
    const float* x   = (const float*)d_in[0];
    const float* pos = (const float*)d_in[1];
    const int*   ei  = (const int*)d_in[2];
    float* out = (float*)d_out;

    // ws layout: [posT 1.6MB][gcur 32KB padded][buckets 14.4MB]
    const size_t posT_b = (size_t)N_NODES * sizeof(float4);             // 1.6 MB
    const size_t gcur_b = 32768;                                        // 391 x 64B padded
    const size_t buck_b = (size_t)NPART * CAP * sizeof(int);            // 14.4 MB

    char* w = (char*)d_ws;
    float4* posT    = (float4*)w;
    int*    gcur    = (int*)(w + posT_b);
    int*    buckets = (int*)(w + posT_b + gcur_b);

    const size_t need_full = posT_b + gcur_b + buck_b;                  // ~16 MB

    const int B = 256;

    if (ws_size >= need_full) {
        hipMemsetAsync(gcur, 0, gcur_b, stream);
        bin_kernel<<<NB, 512, 0, stream>>>((const int4*)ei, x, pos, posT, gcur, buckets);
        part_kernel<<<NPART, 512, 0, stream>>>(gcur, buckets, posT, x, out);
    } else {
        float4* accum = (float4*)(w + posT_b);  // 1.6 MB
        prep_kernel<<<(N_NODES + B - 1) / B, B, 0, stream>>>(x, pos, posT);
        hipMemsetAsync(accum, 0, (size_t)N_NODES * sizeof(float4), stream);
        edge_scatter_atomic_kernel<<<(N_EDGES + B - 1) / B, B, 0, stream>>>(ei, posT, accum);
        finalize_accum_kernel<<<(N_NODES + B - 1) / B, B, 0, stream>>>(x, accum, out);
    }
}

// Round 9
// 115.988 us; speedup vs baseline: 1.6826x; 1.0295x over previous
//
#include <hip/hip_runtime.h>

#define N_NODES 100000
#define N_EDGES 3200000
#define NVEC    (N_EDGES / 4)           // 800000 int4 per stream

#define S_LOG2  8
#define S       (1 << S_LOG2)           // 256 nodes per partition
#define NPART   ((N_NODES + S - 1) / S) // 391 partitions
#define NPB     448                     // NPART padded to x64 for the scan
#define GSTRIDE 16                      // gcur padded to 64B/counter (L2 spread)

#define BT      1024                    // block threads (16 waves)
#define EPB     6252                    // edges per bin block (mult of 4)
#define NB      ((N_EDGES + EPB - 1) / EPB)  // 512 blocks
#define CAP     9216                    // bucket capacity (mean 8184, +11 sigma)
#define KPT     9                       // part: max bucket entries per thread (9*1024=9216)

constexpr float DSIGMA_DT  = -0.0001f;
constexpr float PHI_THRESH = 0.3f;
constexpr float EPS        = 1e-8f;

// ---------------- Pass A: counting-sort edges into 391 partition buckets ---
// Same structure as R8 (proven): 1 returning LDS atomic/edge rank capture,
// in-LDS sort, dense coalesced copy-out (~16-entry = 64B runs per bin).
// CHANGE: 1024-thread blocks -> 2 resident blocks x 16 waves = 32 waves/CU
// (100% occupancy, was 16) to cover the load->atomic->store latency chains.
// VGPR ~25 << 64 cap from launch_bounds(1024,8), so occupancy holds.
__global__ __launch_bounds__(BT, 8) void bin_kernel(const int4* __restrict__ ei4,
                                                    const float* __restrict__ x,
                                                    const float* __restrict__ pos,
                                                    float4* __restrict__ posT,
                                                    int* __restrict__ gcur,
                                                    int* __restrict__ buckets) {
    __shared__ int   lbuf[EPB];            // 25 KB sorted entries (sk<<8 | dk&255)
    __shared__ unsigned short lrk[EPB];    // 12.5 KB per-entry rank
    __shared__ unsigned short lbinS[EPB];  // 12.5 KB bin id of sorted entry
    __shared__ int hist[NPB], lofs[NPB];   // 3.5 KB
    __shared__ int baseg[NPART];           // 1.6 KB
    const int tid = threadIdx.x;

    // fused prep: slice of posT
    {
        const int per = (N_NODES + NB - 1) / NB;   // 196
        const int lo = blockIdx.x * per;
        const int hi = min(lo + per, N_NODES);
        for (int i = lo + tid; i < hi; i += BT)
            posT[i] = make_float4(pos[3 * i], pos[3 * i + 1], pos[3 * i + 2],
                                  x[9 * i + 3]);
    }

    const int ebase = blockIdx.x * EPB;
    const int n  = min(EPB, N_EDGES - ebase);   // multiple of 4
    const int nv = n >> 2;
    const int4* __restrict__ src4 = ei4 + (ebase >> 2);
    const int4* __restrict__ dst4 = ei4 + NVEC + (ebase >> 2);

    for (int i = tid; i < NPB; i += BT) hist[i] = 0;
    __syncthreads();

    // loop 1: histogram with rank capture (1 returning LDS atomic per edge)
    for (int v = tid; v < nv; v += BT) {
        int4 d = dst4[v];
        ushort4 rk;
        rk.x = (unsigned short)atomicAdd(&hist[d.x >> S_LOG2], 1);
        rk.y = (unsigned short)atomicAdd(&hist[d.y >> S_LOG2], 1);
        rk.z = (unsigned short)atomicAdd(&hist[d.z >> S_LOG2], 1);
        rk.w = (unsigned short)atomicAdd(&hist[d.w >> S_LOG2], 1);
        ((ushort4*)lrk)[v] = rk;
    }
    __syncthreads();

    // wave-0 exclusive prefix over 448 padded bins (7 x 64 with carry)
    if (tid < 64) {
        int carry = 0;
        for (int b = 0; b < NPB; b += 64) {
            int v = hist[b + tid];
            int orig = v;
#pragma unroll
            for (int d = 1; d < 64; d <<= 1) {
                int t = __shfl_up(v, d, 64);
                if (tid >= d) v += t;
            }
            lofs[b + tid] = carry + v - orig;
            carry += __shfl(v, 63, 64);
        }
    }
    __syncthreads();
    if (tid < NPART)
        baseg[tid] = atomicAdd(&gcur[tid * GSTRIDE], hist[tid]);
    __syncthreads();

    // loop 2: re-read edge slice (L2-hot), place entries with plain writes
    for (int v = tid; v < nv; v += BT) {
        int4 s = src4[v];
        int4 d = dst4[v];
        ushort4 rk = ((const ushort4*)lrk)[v];
#pragma unroll
        for (int k = 0; k < 4; ++k) {
            int dk = k == 0 ? d.x : k == 1 ? d.y : k == 2 ? d.z : d.w;
            int sk = k == 0 ? s.x : k == 1 ? s.y : k == 2 ? s.z : s.w;
            int rr = k == 0 ? rk.x : k == 1 ? rk.y : k == 2 ? rk.z : rk.w;
            int bin = dk >> S_LOG2;
            int pos = lofs[bin] + rr;
            lbuf[pos]  = (sk << S_LOG2) | (dk & (S - 1));
            lbinS[pos] = (unsigned short)bin;
        }
    }
    __syncthreads();

    // dense coalesced copy-out (~16-entry = 64B runs per bin)
    for (int i = tid; i < n; i += BT) {
        int b   = lbinS[i];
        int pos = baseg[b] + (i - lofs[b]);
        if (pos < CAP) buckets[(size_t)b * CAP + pos] = lbuf[i];
    }
}

// ---------------- Pass B: one block per partition, fused finalize ----------
// Same structure as R8 (proven): register-held entries+ranks, 1 returning
// LDS atomic/edge, scatter to node order, segmented register reduce, fused
// epilogue. CHANGE: 1024-thread blocks -> all 391 blocks co-resident
// (2/CU capacity at 42.9 KB LDS) -> no 2-round makespan quantization; the
// reduce uses 4 threads/node with quad shuffle combine (1024 = 256*4).
__global__ __launch_bounds__(BT, 8) void part_kernel(
        const int* __restrict__ gcur,
        const int* __restrict__ buckets,
        const float4* __restrict__ posT,
        const float* __restrict__ x,
        float* __restrict__ out) {
    __shared__ int S2[CAP];                // 36 KB dst-sorted src ids
    __shared__ int hist[S], base[S];       // 2 KB
    __shared__ float4 ploc[S];             // 4 KB partition's posT slice
    const int p = blockIdx.x, tid = threadIdx.x;
    const int lo = p << S_LOG2;

    if (tid < S) {
        hist[tid] = 0;
        int node = lo + tid;
        ploc[tid] = (node < N_NODES) ? posT[node] : make_float4(0.f, 0.f, 0.f, 0.f);
    }
    const int len = min(gcur[p * GSTRIDE], CAP);
    const int* __restrict__ bp = buckets + (size_t)p * CAP;
    __syncthreads();

    // pass 1: load entries to registers + rank capture (1 LDS atomic/edge)
    int ent[KPT];
    unsigned short prk[KPT];
#pragma unroll
    for (int k = 0; k < KPT; ++k) {
        int i = tid + k * BT;
        ent[k] = 0;
        if (i < len) {
            ent[k] = bp[i];
            prk[k] = (unsigned short)atomicAdd(&hist[ent[k] & (S - 1)], 1);
        }
    }
    __syncthreads();

    // exclusive prefix scan of hist[0..256) by wave 0 (4 x 64 with carry)
    if (tid < 64) {
        int carry = 0;
        for (int b = 0; b < S; b += 64) {
            int v = hist[b + tid];
            int orig = v;
#pragma unroll
            for (int d = 1; d < 64; d <<= 1) {
                int t = __shfl_up(v, d, 64);
                if (tid >= d) v += t;
            }
            base[b + tid] = carry + v - orig;
            carry += __shfl(v, 63, 64);
        }
    }
    __syncthreads();

    // pass 2: scatter from registers into dst-sorted order (1 LDS write/edge)
#pragma unroll
    for (int k = 0; k < KPT; ++k) {
        int i = tid + k * BT;
        if (i < len)
            S2[base[ent[k] & (S - 1)] + (int)prk[k]] = ent[k] >> S_LOG2;
    }
    __syncthreads();

    // fused reduce + finalize: 4 threads per node, quad shuffle combine.
    // tid = r*4 + q ; rows r in [0,256), q in [0,4). 1024 = S*4 exactly.
    const int r = tid >> 2, q = tid & 3;
    const int node = lo + r;
    const int nseg = hist[r];
    const int b0 = base[r];
    float4 b = ploc[r];
    float ax = 0.f, ay = 0.f, az = 0.f;
    for (int j = b0 + q; j < b0 + nseg; j += 4) {
        float4 a = posT[S2[j]];
        float px = a.x - b.x, py = a.y - b.y, pz = a.z - b.z;
        float dT = a.w - b.w;
        float w  = dT / (px * px + py * py + pz * pz + EPS);
        ax += w * px; ay += w * py; az += w * pz;
    }
    // combine q=0..3 (lanes r*4..r*4+3 are contiguous within a wave)
    ax += __shfl_down(ax, 2, 64); ax += __shfl_down(ax, 1, 64);
    ay += __shfl_down(ay, 2, 64); ay += __shfl_down(ay, 1, 64);
    az += __shfl_down(az, 2, 64); az += __shfl_down(az, 1, 64);
    if (q == 0 && node < N_NODES) {
        float phi = x[node * 9 + 8];
        float cn = nseg > 1 ? (float)nseg : 1.0f;
        float m = (fabsf(phi) < PHI_THRESH) ? (DSIGMA_DT / cn) : 0.0f;
        out[3 * node]     = m * ax;
        out[3 * node + 1] = m * ay;
        out[3 * node + 2] = m * az;
    }
}

// ---------------- fallback: global atomics (small ws) ---------------------
__global__ void prep_kernel(const float* __restrict__ x,
                            const float* __restrict__ pos,
                            float4* __restrict__ posT) {
    int i = blockIdx.x * blockDim.x + threadIdx.x;
    if (i < N_NODES)
        posT[i] = make_float4(pos[3 * i], pos[3 * i + 1], pos[3 * i + 2],
                              x[9 * i + 3]);
}

__global__ void edge_scatter_atomic_kernel(const int* __restrict__ ei,
                                           const float4* __restrict__ posT,
                                           float4* __restrict__ accum) {
    int e = blockIdx.x * blockDim.x + threadIdx.x;
    if (e >= N_EDGES) return;
    int s = ei[e];
    int d = ei[N_EDGES + e];
    float4 a = posT[s];
    float4 b = posT[d];
    float px = a.x - b.x, py = a.y - b.y, pz = a.z - b.z;
    float dT = a.w - b.w;
    float w  = dT / (px * px + py * py + pz * pz + EPS);
    float* ac = (float*)&accum[d];
    atomicAdd(ac,     w * px);
    atomicAdd(ac + 1, w * py);
    atomicAdd(ac + 2, w * pz);
    atomicAdd(ac + 3, 1.0f);
}

__global__ void finalize_accum_kernel(const float* __restrict__ x,
                                      const float4* __restrict__ accum,
                                      float* __restrict__ out) {
    int i = blockIdx.x * blockDim.x + threadIdx.x;
    if (i >= N_NODES) return;
    float4 a = accum[i];
    float phi = x[i * 9 + 8];
    float cn = a.w > 1.0f ? a.w : 1.0f;
    float m = (fabsf(phi) < PHI_THRESH) ? (DSIGMA_DT / cn) : 0.0f;
    out[3 * i]     = m * a.x;
    out[3 * i + 1] = m * a.y;
    out[3 * i + 2] = m * a.z;
}

extern "C" void kernel_launch(void* const* d_in, const int* in_sizes, int n_in,
                              void* d_out, int out_size, void* d_ws, size_t ws_size,
                              hipStream_t stream) {
    const float* x   = (const float*)d_in[0];
    const float* pos = (const float*)d_in[1];
    const int*   ei  = (const int*)d_in[2];
    float* out = (float*)d_out;

    // ws layout: [posT 1.6MB][gcur 32KB padded][buckets 14.4MB]
    const size_t posT_b = (size_t)N_NODES * sizeof(float4);             // 1.6 MB
    const size_t gcur_b = 32768;                                        // 391 x 64B padded
    const size_t buck_b = (size_t)NPART * CAP * sizeof(int);            // 14.4 MB

    char* w = (char*)d_ws;
    float4* posT    = (float4*)w;
    int*    gcur    = (int*)(w + posT_b);
    int*    buckets = (int*)(w + posT_b + gcur_b);

    const size_t need_full = posT_b + gcur_b + buck_b;                  // ~16 MB

    const int B = 256;

    if (ws_size >= need_full) {
        hipMemsetAsync(gcur, 0, gcur_b, stream);
        bin_kernel<<<NB, BT, 0, stream>>>((const int4*)ei, x, pos, posT, gcur, buckets);
        part_kernel<<<NPART, BT, 0, stream>>>(gcur, buckets, posT, x, out);
    } else {
        float4* accum = (float4*)(w + posT_b);  // 1.6 MB
        prep_kernel<<<(N_NODES + B - 1) / B, B, 0, stream>>>(x, pos, posT);
        hipMemsetAsync(accum, 0, (size_t)N_NODES * sizeof(float4), stream);
        edge_scatter_atomic_kernel<<<(N_EDGES + B - 1) / B, B, 0, stream>>>(ei, posT, accum);
        finalize_accum_kernel<<<(N_NODES + B - 1) / B, B, 0, stream>>>(x, accum, out);
    }
}